// Round 4
// baseline (353.044 us; speedup 1.0000x reference)
//
#include <hip/hip_runtime.h>

#define NN 50000
#define NE 800000

typedef __attribute__((ext_vector_type(8))) short short8;
typedef __attribute__((ext_vector_type(4))) float f32x4;

// ---------------------------------------------------------------------------
// Algebraic reduction (verified): softmax weights per (node,head) sum to 1, so
//   agg[n] = v[n] * (indegree(n)>0), and
//   out = LN(nodes + bo + mask * (nodes @ (Wv@Wo) + bv@Wo)).
// GEMM runs on bf16 MFMA with a 3-term Dekker split (rel err ~2^-16, invisible
// vs absmax 0.0156). Chain: memsetAsync(mask) -> prep_scatter -> fused.
// MFMA layouts (learn_hip-verified): A row=lane&15, k=8*(lane>>4)+e (contig 8);
// B col=lane&15, same k; D col=lane&15, row=4*(lane>>4)+reg.
// ws layout: Bhi[16384 u16] | Blo[16384 u16] | bc[128 f32] | mask[NN] int
// ---------------------------------------------------------------------------

__device__ __forceinline__ unsigned rne_bf16(float v) {
    unsigned u = __float_as_uint(v);
    return (u + 0x7FFFu + ((u >> 16) & 1u)) >> 16;
}

// Blocks 0..63: Wc = Wv@Wo packed to bf16 hi/lo MFMA fragments; block 64:
// bc = bv@Wo; blocks 65+: indegree scatter. All independent -> concurrent.
__global__ __launch_bounds__(256) void prep_scatter_kernel(
    const float* __restrict__ Wv, const float* __restrict__ bv,
    const float* __restrict__ Wo, const int* __restrict__ tgt,
    unsigned short* __restrict__ Bhi, unsigned short* __restrict__ Blo,
    float* __restrict__ bc, int* __restrict__ mask)
{
    int b = blockIdx.x, t = threadIdx.x;
    if (b < 64) {
        int k = 2 * b + (t >> 7);   // Wc row (K index)
        int n = t & 127;            // Wc col (N index)
        float acc = 0.f;
        #pragma unroll 4
        for (int m = 0; m < 128; ++m)
            acc = fmaf(Wv[k * 128 + m], Wo[m * 128 + n], acc);
        unsigned hb = rne_bf16(acc);
        float res = acc - __uint_as_float(hb << 16);
        unsigned lb = rne_bf16(res);
        // fragment-linear index: [kstep s][ntile][lane][e]
        int s = k >> 5, kk = k & 31, g = kk >> 3, e = kk & 7;
        int lane = (g << 4) | (n & 15), tn = n >> 4;
        int idx = (((s * 8 + tn) * 64) + lane) * 8 + e;
        Bhi[idx] = (unsigned short)hb;
        Blo[idx] = (unsigned short)lb;
    } else if (b == 64) {
        if (t < 128) {
            float acc = 0.f;
            #pragma unroll 4
            for (int m = 0; m < 128; ++m)
                acc = fmaf(bv[m], Wo[m * 128 + t], acc);
            bc[t] = acc;
        }
    } else {
        int i = (b - 65) * 256 + t;          // int4 index; NE % 4 == 0
        if (i < NE / 4) {
            int4 e = ((const int4*)tgt)[i];
            mask[e.x] = 1; mask[e.y] = 1; mask[e.z] = 1; mask[e.w] = 1;
        }
    }
}

// out = LN(nodes + bo + mask*(nodes@Wc + bc)) via split-bf16 MFMA.
// No LDS, no barriers: each wave owns 16 rows; A-frags straight from global,
// B-frags from the pre-packed fragment arrays (L2-resident, chip-shared).
// Epilogue operands (mask bits, bo/bc/gamma/beta) are hoisted BEFORE the
// K-loop so their latency hides under the MFMA phase.
__global__ __launch_bounds__(256, 4) void fused_kernel(
    const float* __restrict__ nodes,
    const unsigned short* __restrict__ Bhi, const unsigned short* __restrict__ Blo,
    const float* __restrict__ bc, const int* __restrict__ mask,
    const float* __restrict__ bo,
    const float* __restrict__ gamma, const float* __restrict__ beta,
    float* __restrict__ out)
{
    const int lane = threadIdx.x & 63;
    const int wv   = threadIdx.x >> 6;
    const int g    = lane >> 4;
    const int ln   = lane & 15;
    const int Rb   = blockIdx.x * 64 + wv * 16;   // wave's 16-row tile base

    int Ra = Rb + ln;                 // A-side row for this lane
    if (Ra > NN - 1) Ra = NN - 1;     // clamp: duplicate rows never stored
    const float4* arow = (const float4*)(nodes + (long)Ra * 128);

    // ---- epilogue operands issued early (latency hidden under MFMA) ----
    float msk[4];
    #pragma unroll
    for (int r = 0; r < 4; ++r) {
        int Rd = Rb + 4 * g + r;
        int Rc = (Rd > NN - 1) ? NN - 1 : Rd;
        msk[r] = (mask[Rc] != 0) ? 1.f : 0.f;
    }
    float bo8[8], bc8[8], gm8[8], bt8[8];
    #pragma unroll
    for (int t = 0; t < 8; ++t) {
        int c = 16 * t + ln;
        bo8[t] = bo[c]; bc8[t] = bc[c]; gm8[t] = gamma[c]; bt8[t] = beta[c];
    }

    f32x4 acc[8];
    #pragma unroll
    for (int t = 0; t < 8; ++t) { acc[t][0] = 0.f; acc[t][1] = 0.f; acc[t][2] = 0.f; acc[t][3] = 0.f; }

    #pragma unroll
    for (int s = 0; s < 4; ++s) {     // K-steps of 32
        // A fragment: 8 contiguous f32 at k = 32s + 8g (two float4)
        float4 a0 = arow[s * 8 + 2 * g];
        float4 a1 = arow[s * 8 + 2 * g + 1];
        float av[8] = {a0.x, a0.y, a0.z, a0.w, a1.x, a1.y, a1.z, a1.w};
        short8 ahi, alo;
        #pragma unroll
        for (int e = 0; e < 8; ++e) {
            unsigned u = __float_as_uint(av[e]);
            ahi[e] = (short)(u >> 16);                             // trunc-bf16
            float res = av[e] - __uint_as_float(u & 0xFFFF0000u);  // exact
            alo[e] = (short)(__float_as_uint(res) >> 16);
        }
        const short8* bh = (const short8*)(Bhi) + (s * 8) * 64;
        const short8* bl = (const short8*)(Blo) + (s * 8) * 64;
        #pragma unroll
        for (int t = 0; t < 8; ++t) {
            short8 bhv = bh[t * 64 + lane];
            short8 blv = bl[t * 64 + lane];
            acc[t] = __builtin_amdgcn_mfma_f32_16x16x32_bf16(ahi, bhv, acc[t], 0, 0, 0);
            acc[t] = __builtin_amdgcn_mfma_f32_16x16x32_bf16(ahi, blv, acc[t], 0, 0, 0);
            acc[t] = __builtin_amdgcn_mfma_f32_16x16x32_bf16(alo, bhv, acc[t], 0, 0, 0);
        }
    }

    // epilogue: D row = Rb + 4g + r, col = 16t + ln; LN across 16-lane group
    #pragma unroll
    for (int r = 0; r < 4; ++r) {
        int Rd = Rb + 4 * g + r;
        int Rc = (Rd > NN - 1) ? NN - 1 : Rd;
        const float* nrow = nodes + (long)Rc * 128;
        float m = msk[r];
        float x[8];
        float sum = 0.f, ssum = 0.f;
        #pragma unroll
        for (int t = 0; t < 8; ++t) {
            x[t] = nrow[16 * t + ln] + bo8[t] + m * (acc[t][r] + bc8[t]);
            sum  += x[t];
            ssum += x[t] * x[t];
        }
        #pragma unroll
        for (int off = 1; off < 16; off <<= 1) {   // reduce within 16-lane group
            sum  += __shfl_xor(sum, off);
            ssum += __shfl_xor(ssum, off);
        }
        float mu   = sum * (1.f / 128.f);
        float var  = ssum * (1.f / 128.f) - mu * mu;
        float rstd = rsqrtf(var + 1e-5f);
        if (Rd < NN) {
            float* orow = out + (long)Rd * 128;
            #pragma unroll
            for (int t = 0; t < 8; ++t)
                orow[16 * t + ln] = (x[t] - mu) * rstd * gm8[t] + bt8[t];
        }
    }
}

extern "C" void kernel_launch(void* const* d_in, const int* in_sizes, int n_in,
                              void* d_out, int out_size, void* d_ws, size_t ws_size,
                              hipStream_t stream) {
    const float* nodes = (const float*)d_in[0];
    const int*   ei    = (const int*)d_in[2];
    const float* Wv    = (const float*)d_in[9];
    const float* bv    = (const float*)d_in[10];
    const float* Wo    = (const float*)d_in[21];
    const float* bo    = (const float*)d_in[22];
    const float* gamma = (const float*)d_in[23];
    const float* beta  = (const float*)d_in[24];

    unsigned short* Bhi = (unsigned short*)d_ws;          // 16384 u16 = 32 KB
    unsigned short* Blo = Bhi + 16384;                    // 32 KB
    float*          bcp = (float*)(Blo + 16384);          // 128 f32
    int*            mask = (int*)(bcp + 128);             // NN ints

    // mask zero via DMA fill node (graph-capturable), replacing a kernel launch
    hipMemsetAsync(mask, 0, NN * sizeof(int), stream);
    prep_scatter_kernel<<<65 + (NE / 4 + 255) / 256, 256, 0, stream>>>(
        Wv, bv, Wo, ei + NE, Bhi, Blo, bcp, mask);
    fused_kernel<<<(NN + 63) / 64, 256, 0, stream>>>(
        nodes, Bhi, Blo, bcp, mask, bo, gamma, beta, (float*)d_out);
}

// Round 5
// 328.110 us; speedup vs baseline: 1.0760x; 1.0760x over previous
//
#include <hip/hip_runtime.h>

#define NN 50000
#define NE 800000

typedef __attribute__((ext_vector_type(8))) short short8;
typedef __attribute__((ext_vector_type(4))) float f32x4;

// ---------------------------------------------------------------------------
// Algebraic reduction (verified): softmax weights per (node,head) sum to 1, so
//   agg[n] = v[n] * (indegree(n)>0), and
//   out = LN(nodes + bo + mask * (nodes @ (Wv@Wo) + bv@Wo)).
// GEMM on bf16 MFMA with a 3-term Dekker split (rel err ~2^-16, invisible vs
// absmax 0.0156). This is the round-3 configuration (session best, 325.6 us):
// round-4's memsetAsync + operand-hoist both reverted after a 27 us regression.
// MFMA layouts (learn_hip-verified): A row=lane&15, k=8*(lane>>4)+e (contig 8);
// B col=lane&15, same k; D col=lane&15, row=4*(lane>>4)+reg.
// ws layout: Bhi[16384 u16] | Blo[16384 u16] | bc[128 f32] | mask[NN] int
// ---------------------------------------------------------------------------

__device__ __forceinline__ unsigned rne_bf16(float v) {
    unsigned u = __float_as_uint(v);
    return (u + 0x7FFFu + ((u >> 16) & 1u)) >> 16;
}

// Kernel A: zero the indegree mask.
__global__ __launch_bounds__(256) void init_mask_kernel(int* __restrict__ mask)
{
    int i = blockIdx.x * 256 + threadIdx.x;   // int4 index; NN % 4 == 0
    if (i < NN / 4) ((int4*)mask)[i] = make_int4(0, 0, 0, 0);
}

// Kernel B: blocks 0..63 compute Wc = Wv@Wo and pack bf16 hi/lo fragments in
// MFMA fragment-linear order; block 64 computes bc = bv@Wo; blocks 65+ scatter
// the indegree mask. All three parts independent -> run concurrently.
__global__ __launch_bounds__(256) void prep_scatter_kernel(
    const float* __restrict__ Wv, const float* __restrict__ bv,
    const float* __restrict__ Wo, const int* __restrict__ tgt,
    unsigned short* __restrict__ Bhi, unsigned short* __restrict__ Blo,
    float* __restrict__ bc, int* __restrict__ mask)
{
    int b = blockIdx.x, t = threadIdx.x;
    if (b < 64) {
        int k = 2 * b + (t >> 7);   // Wc row (K index)
        int n = t & 127;            // Wc col (N index)
        float acc = 0.f;
        #pragma unroll 4
        for (int m = 0; m < 128; ++m)
            acc = fmaf(Wv[k * 128 + m], Wo[m * 128 + n], acc);
        unsigned hb = rne_bf16(acc);
        float res = acc - __uint_as_float(hb << 16);
        unsigned lb = rne_bf16(res);
        // fragment-linear index: [kstep s][ntile][lane][e]
        int s = k >> 5, kk = k & 31, g = kk >> 3, e = kk & 7;
        int lane = (g << 4) | (n & 15), tn = n >> 4;
        int idx = (((s * 8 + tn) * 64) + lane) * 8 + e;
        Bhi[idx] = (unsigned short)hb;
        Blo[idx] = (unsigned short)lb;
    } else if (b == 64) {
        if (t < 128) {
            float acc = 0.f;
            #pragma unroll 4
            for (int m = 0; m < 128; ++m)
                acc = fmaf(bv[m], Wo[m * 128 + t], acc);
            bc[t] = acc;
        }
    } else {
        int i = (b - 65) * 256 + t;          // int4 index; NE % 4 == 0
        if (i < NE / 4) {
            int4 e = ((const int4*)tgt)[i];
            mask[e.x] = 1; mask[e.y] = 1; mask[e.z] = 1; mask[e.w] = 1;
        }
    }
}

// Kernel C: out = LN(nodes + bo + mask*(nodes@Wc + bc)) via split-bf16 MFMA.
// No LDS, no barriers: each wave owns 16 rows; A-frags straight from global,
// B-frags from the pre-packed fragment arrays (L2-resident, chip-shared).
__global__ __launch_bounds__(256, 4) void fused_kernel(
    const float* __restrict__ nodes,
    const unsigned short* __restrict__ Bhi, const unsigned short* __restrict__ Blo,
    const float* __restrict__ bc, const int* __restrict__ mask,
    const float* __restrict__ bo,
    const float* __restrict__ gamma, const float* __restrict__ beta,
    float* __restrict__ out)
{
    const int lane = threadIdx.x & 63;
    const int wv   = threadIdx.x >> 6;
    const int g    = lane >> 4;
    const int ln   = lane & 15;
    const int Rb   = blockIdx.x * 64 + wv * 16;   // wave's 16-row tile base

    int Ra = Rb + ln;                 // A-side row for this lane
    if (Ra > NN - 1) Ra = NN - 1;     // clamp: duplicate rows never stored
    const float4* arow = (const float4*)(nodes + (long)Ra * 128);

    f32x4 acc[8];
    #pragma unroll
    for (int t = 0; t < 8; ++t) { acc[t][0] = 0.f; acc[t][1] = 0.f; acc[t][2] = 0.f; acc[t][3] = 0.f; }

    #pragma unroll
    for (int s = 0; s < 4; ++s) {     // K-steps of 32
        // A fragment: 8 contiguous f32 at k = 32s + 8g (two float4)
        float4 a0 = arow[s * 8 + 2 * g];
        float4 a1 = arow[s * 8 + 2 * g + 1];
        float av[8] = {a0.x, a0.y, a0.z, a0.w, a1.x, a1.y, a1.z, a1.w};
        short8 ahi, alo;
        #pragma unroll
        for (int e = 0; e < 8; ++e) {
            unsigned u = __float_as_uint(av[e]);
            ahi[e] = (short)(u >> 16);                             // trunc-bf16
            float res = av[e] - __uint_as_float(u & 0xFFFF0000u);  // exact
            alo[e] = (short)(__float_as_uint(res) >> 16);
        }
        const short8* bh = (const short8*)(Bhi) + (s * 8) * 64;
        const short8* bl = (const short8*)(Blo) + (s * 8) * 64;
        #pragma unroll
        for (int t = 0; t < 8; ++t) {
            short8 bhv = bh[t * 64 + lane];
            short8 blv = bl[t * 64 + lane];
            acc[t] = __builtin_amdgcn_mfma_f32_16x16x32_bf16(ahi, bhv, acc[t], 0, 0, 0);
            acc[t] = __builtin_amdgcn_mfma_f32_16x16x32_bf16(ahi, blv, acc[t], 0, 0, 0);
            acc[t] = __builtin_amdgcn_mfma_f32_16x16x32_bf16(alo, bhv, acc[t], 0, 0, 0);
        }
    }

    // per-column parameters (col = 16t + ln), reused across the 4 output rows
    float bo8[8], bc8[8], gm8[8], bt8[8];
    #pragma unroll
    for (int t = 0; t < 8; ++t) {
        int c = 16 * t + ln;
        bo8[t] = bo[c]; bc8[t] = bc[c]; gm8[t] = gamma[c]; bt8[t] = beta[c];
    }

    // epilogue: D row = Rb + 4g + r, col = 16t + ln; LN across the 16-lane group
    #pragma unroll
    for (int r = 0; r < 4; ++r) {
        int Rd = Rb + 4 * g + r;
        int Rc = (Rd > NN - 1) ? NN - 1 : Rd;
        float m = (mask[Rc] != 0) ? 1.f : 0.f;
        const float* nrow = nodes + (long)Rc * 128;
        float x[8];
        float sum = 0.f, ssum = 0.f;
        #pragma unroll
        for (int t = 0; t < 8; ++t) {
            x[t] = nrow[16 * t + ln] + bo8[t] + m * (acc[t][r] + bc8[t]);
            sum  += x[t];
            ssum += x[t] * x[t];
        }
        #pragma unroll
        for (int off = 1; off < 16; off <<= 1) {   // reduce within 16-lane group
            sum  += __shfl_xor(sum, off);
            ssum += __shfl_xor(ssum, off);
        }
        float mu   = sum * (1.f / 128.f);
        float var  = ssum * (1.f / 128.f) - mu * mu;
        float rstd = rsqrtf(var + 1e-5f);
        if (Rd < NN) {
            float* orow = out + (long)Rd * 128;
            #pragma unroll
            for (int t = 0; t < 8; ++t)
                orow[16 * t + ln] = (x[t] - mu) * rstd * gm8[t] + bt8[t];
        }
    }
}

extern "C" void kernel_launch(void* const* d_in, const int* in_sizes, int n_in,
                              void* d_out, int out_size, void* d_ws, size_t ws_size,
                              hipStream_t stream) {
    const float* nodes = (const float*)d_in[0];
    const int*   ei    = (const int*)d_in[2];
    const float* Wv    = (const float*)d_in[9];
    const float* bv    = (const float*)d_in[10];
    const float* Wo    = (const float*)d_in[21];
    const float* bo    = (const float*)d_in[22];
    const float* gamma = (const float*)d_in[23];
    const float* beta  = (const float*)d_in[24];

    unsigned short* Bhi = (unsigned short*)d_ws;          // 16384 u16 = 32 KB
    unsigned short* Blo = Bhi + 16384;                    // 32 KB
    float*          bcp = (float*)(Blo + 16384);          // 128 f32
    int*            mask = (int*)(bcp + 128);             // NN ints (16B-aligned)

    init_mask_kernel<<<(NN / 4 + 255) / 256, 256, 0, stream>>>(mask);
    prep_scatter_kernel<<<65 + (NE / 4 + 255) / 256, 256, 0, stream>>>(
        Wv, bv, Wo, ei + NE, Bhi, Blo, bcp, mask);
    fused_kernel<<<(NN + 63) / 64, 256, 0, stream>>>(
        nodes, Bhi, Blo, bcp, mask, bo, gamma, beta, (float*)d_out);
}